// Round 17
// baseline (286.804 us; speedup 1.0000x reference)
//
#include <hip/hip_runtime.h>
#include <hip/hip_bf16.h>

#define DEV __device__ __forceinline__

typedef __attribute__((ext_vector_type(8))) __bf16 bf16x8;
typedef __attribute__((ext_vector_type(4))) float f32x4;

// ---------- bf16 helpers (bit-level) ----------
DEV float bfu(unsigned short u) { return __uint_as_float((unsigned int)u << 16); }
DEV unsigned short f2bf(float f) {
    union { float f; unsigned int u; } cv; cv.f = f;
    unsigned int u = cv.u;
    unsigned int r = (u + 0x7fffu + ((u >> 16) & 1u)) >> 16;  // RNE
    return (unsigned short)r;
}
DEV unsigned int pack2(float a, float b) {
    return (unsigned int)f2bf(a) | ((unsigned int)f2bf(b) << 16);
}
// bank-conflict swizzle for scalar-accessed ct tile (word-granular XOR)
DEV int cs(int row, int col) { return col ^ ((row & 15) << 1); }

// dims: B=16 N=32 D=64 H=8 S=8 LT=128 DE=256 L=16
// BN=512 BH=128 NS=256 DL=1024 DQKV=1536

// ---------- fused GroupNorm stats + normalize + transpose: x -> xnt[bn][130][64] ----------
// grid 512, block 256
__global__ __launch_bounds__(256) void gnx_kernel(const float* __restrict__ src,
    const float* __restrict__ gamma, const float* __restrict__ beta,
    unsigned short* __restrict__ xnt)
{
    __shared__ __align__(16) float sx[64][133];
    __shared__ float gsum[8], gsq[8], la[64], lb[64];
    const int s = blockIdx.x, tid = threadIdx.x;
    for (int idx = tid; idx < 8192; idx += 256) {
        int c = idx >> 7, lt = idx & 127;
        sx[c][lt] = src[(size_t)s * 8192 + idx];
    }
    __syncthreads();
    const int g = tid >> 5, il = tid & 31;
    float sm = 0.f, sq = 0.f;
    #pragma unroll
    for (int m = 0; m < 32; ++m) {
        int e = il + m * 32;
        float v = sx[g * 8 + (e >> 7)][e & 127];
        sm += v; sq += v * v;
    }
    #pragma unroll
    for (int m = 16; m; m >>= 1) { sm += __shfl_xor(sm, m); sq += __shfl_xor(sq, m); }
    if (il == 0) { gsum[g] = sm; gsq[g] = sq; }
    __syncthreads();
    if (tid < 64) {
        int gg = tid >> 3;
        float mu = gsum[gg] * (1.f / 1024.f);
        float var = gsq[gg] * (1.f / 1024.f) - mu * mu;
        float a = gamma[tid] * rsqrtf(var + 1e-5f);
        la[tid] = a; lb[tid] = beta[tid] - mu * a;
    }
    __syncthreads();
    for (int idx = tid; idx < 8320; idx += 256) {
        int row = idx >> 6, c = idx & 63;
        float v = 0.f;
        if (row >= 1 && row <= 128) v = sx[c][row - 1] * la[c] + lb[c];
        xnt[(size_t)s * 8320 + idx] = f2bf(v);
    }
}

// ---------- generic weight prep ----------
__global__ __launch_bounds__(256) void prep_w_kernel(const float* __restrict__ w,
    unsigned short* __restrict__ dst, int n)
{
    int i = blockIdx.x * 256 + threadIdx.x;
    if (i < n) {
        #pragma unroll
        for (int k = 0; k < 3; ++k)
            dst[k * n + i] = f2bf(w[(size_t)i * 3 + k]);
    }
}

// ---------- QKV conv via MFMA; q/k/v token-major coalesced; fused q/k norms ----------
// grid (CH*32 scenes, 12 chunks) -> same-scene blocks co-locate on one XCD
__global__ __launch_bounds__(256, 3) void conv_qkv_mfma(
    const unsigned short* __restrict__ xnt,
    const unsigned short* __restrict__ wq, const float* __restrict__ bias,
    unsigned short* __restrict__ qb, unsigned short* __restrict__ kb,
    unsigned short* __restrict__ vt, float* __restrict__ nq, float* __restrict__ nk,
    int b0)
{
    __shared__ __align__(16) char smem[34816];
    unsigned short (*xt)[72]  = (unsigned short(*)[72])smem;   // [130][72]
    unsigned short (*ct)[136] = (unsigned short(*)[136])smem;  // [128][136] overlay

    const int sl = blockIdx.x, mc = blockIdx.y, tid = threadIdx.x;
    const int bn = b0 * 32 + sl;
    const int w = tid >> 6, lane = tid & 63;
    const int lrow = lane & 15, lko = (lane >> 4) * 8, q4 = lane >> 4;

    bf16x8 af[3][2][2];
    #pragma unroll
    for (int k = 0; k < 3; ++k)
        #pragma unroll
        for (int kc = 0; kc < 2; ++kc)
            #pragma unroll
            for (int m = 0; m < 2; ++m)
                af[k][kc][m] = *(const bf16x8*)(wq + (size_t)k * 98304 +
                    (size_t)(mc * 128 + w * 32 + m * 16 + lrow) * 64 + kc * 32 + lko);

    for (int idx = tid; idx < 1040; idx += 256)
        *(uint4*)&xt[idx >> 3][(idx & 7) * 8] = *(const uint4*)(xnt + (size_t)bn * 8320 + idx * 8);
    __syncthreads();

    f32x4 acc[2][8];
    #pragma unroll
    for (int m = 0; m < 2; ++m)
        #pragma unroll
        for (int n = 0; n < 8; ++n) acc[m][n] = (f32x4)0.f;
    #pragma unroll
    for (int k = 0; k < 3; ++k) {
        #pragma unroll
        for (int kc = 0; kc < 2; ++kc) {
            #pragma unroll
            for (int n = 0; n < 8; ++n) {
                bf16x8 b = *(const bf16x8*)&xt[n * 16 + lrow + k][kc * 32 + lko];
                acc[0][n] = __builtin_amdgcn_mfma_f32_16x16x32_bf16(af[k][kc][0], b, acc[0][n], 0, 0, 0);
                acc[1][n] = __builtin_amdgcn_mfma_f32_16x16x32_bf16(af[k][kc][1], b, acc[1][n], 0, 0, 0);
            }
        }
    }
    __syncthreads();   // xt dead; reuse as ct
    const int c0 = mc * 128;
    float bv[2][4];
    #pragma unroll
    for (int m = 0; m < 2; ++m)
        #pragma unroll
        for (int r = 0; r < 4; ++r)
            bv[m][r] = bias[c0 + w * 32 + m * 16 + q4 * 4 + r];
    #pragma unroll
    for (int m = 0; m < 2; ++m)
        #pragma unroll
        for (int n = 0; n < 8; ++n)
            #pragma unroll
            for (int r = 0; r < 4; ++r) {
                int row = w * 32 + m * 16 + q4 * 4 + r;
                ct[row][cs(row, n * 16 + lrow)] = f2bf(acc[m][n][r] + bv[m][r]);
            }
    __syncthreads();
    const int t = mc >> 2, h_base = (mc & 3) * 2;
    const int bl = sl >> 5, n_tr = sl & 31;
    unsigned short* dst = (t == 0) ? qb : ((t == 1) ? kb : vt);
    for (int idx = tid; idx < 2048; idx += 256) {
        int lb = idx & 1;
        int d  = (idx >> 1) & 63;
        int s  = (idx >> 7) & 7;
        int hl = idx >> 10;
        int row = hl * 64 + d;
        unsigned int uu[4];
        #pragma unroll
        for (int e2 = 0; e2 < 4; ++e2) {
            unsigned short w0 = ct[row][cs(row, (lb * 8 + e2 * 2) * 8 + s)];
            unsigned short w1 = ct[row][cs(row, (lb * 8 + e2 * 2 + 1) * 8 + s)];
            uu[e2] = (unsigned int)w0 | ((unsigned int)w1 << 16);
        }
        uint4 o = {uu[0], uu[1], uu[2], uu[3]};
        size_t a = ((size_t)((bl * 8 + h_base + hl) * 256 + n_tr * 8 + s)) * 1024 + d * 16 + lb * 8;
        *(uint4*)(dst + a) = o;
    }
    if (t < 2) {
        float* ndst = t ? nk : nq;
        const int tk = tid >> 4, l = tid & 15;
        const int hl = tk >> 3, sS = tk & 7;
        float s2 = 0.f;
        for (int d = 0; d < 64; ++d) {
            int row = hl * 64 + d;
            float v = bfu(ct[row][cs(row, l * 8 + sS)]);
            s2 = fmaf(v, v, s2);
        }
        #pragma unroll
        for (int m = 8; m; m >>= 1) s2 += __shfl_xor(s2, m);
        if (l == 0)
            ndst[(bl * 8 + h_base + hl) * 256 + n_tr * 8 + sS] = s2;
    }
}

// ---------- attn weights via MFMA: S=QK^T, W=rsqrt(nq+nk-2S) ----------
// grid (CH*8 bh, 2 i0, 2 j0) -> same-bh blocks co-locate on one XCD
__global__ __launch_bounds__(256) void attnw_mfma(const unsigned short* __restrict__ qb,
    const unsigned short* __restrict__ kb, const float* __restrict__ nq,
    const float* __restrict__ nk, unsigned short* __restrict__ attn)
{
    __shared__ __align__(16) unsigned short q_s[128][136];
    __shared__ __align__(16) unsigned short k_s[128][136];
    const int bh = blockIdx.x, i0 = blockIdx.y * 128, j0 = blockIdx.z * 128;
    const int tid = threadIdx.x, w = tid >> 6, lane = tid & 63;
    const int wi = w >> 1, wj = w & 1;
    const int lrow = lane & 15, lko = (lane >> 4) * 8;
    f32x4 acc[4][4];
    #pragma unroll
    for (int m = 0; m < 4; ++m)
        #pragma unroll
        for (int n = 0; n < 4; ++n) acc[m][n] = (f32x4)0.f;
    const size_t tb = (size_t)bh * 262144;
    for (int fc = 0; fc < 8; ++fc) {
        __syncthreads();
        for (int idx = tid; idx < 2048; idx += 256) {
            int r = idx >> 4, c8 = (idx & 15) * 8;
            *(uint4*)&q_s[r][c8] = *(const uint4*)(qb + tb + (size_t)(i0 + r) * 1024 + fc * 128 + c8);
            *(uint4*)&k_s[r][c8] = *(const uint4*)(kb + tb + (size_t)(j0 + r) * 1024 + fc * 128 + c8);
        }
        __syncthreads();
        #pragma unroll
        for (int ks = 0; ks < 4; ++ks) {
            bf16x8 a[4], b[4];
            #pragma unroll
            for (int m = 0; m < 4; ++m) a[m] = *(const bf16x8*)&q_s[wi * 64 + m * 16 + lrow][ks * 32 + lko];
            #pragma unroll
            for (int n = 0; n < 4; ++n) b[n] = *(const bf16x8*)&k_s[wj * 64 + n * 16 + lrow][ks * 32 + lko];
            #pragma unroll
            for (int m = 0; m < 4; ++m)
                #pragma unroll
                for (int n = 0; n < 4; ++n)
                    acc[m][n] = __builtin_amdgcn_mfma_f32_16x16x32_bf16(a[m], b[n], acc[m][n], 0, 0, 0);
        }
    }
    float nqv[4][4], nkv[4];
    #pragma unroll
    for (int m = 0; m < 4; ++m)
        #pragma unroll
        for (int r = 0; r < 4; ++r)
            nqv[m][r] = nq[bh * 256 + i0 + wi * 64 + m * 16 + (lane >> 4) * 4 + r];
    #pragma unroll
    for (int n = 0; n < 4; ++n)
        nkv[n] = nk[bh * 256 + j0 + wj * 64 + n * 16 + lrow];
    __syncthreads();
    #pragma unroll
    for (int m = 0; m < 4; ++m)
        #pragma unroll
        for (int n = 0; n < 4; ++n)
            #pragma unroll
            for (int r = 0; r < 4; ++r) {
                float sq = nqv[m][r] + nkv[n] - 2.f * acc[m][n][r];
                q_s[wi * 64 + m * 16 + (lane >> 4) * 4 + r][wj * 64 + n * 16 + lrow] =
                    f2bf(rsqrtf(fmaxf(sq, 1e-12f)));
            }
    __syncthreads();
    for (int idx = tid; idx < 2048; idx += 256) {
        int r = idx >> 4, c8 = (idx & 15) * 8;
        *(uint4*)(attn + (size_t)bh * 65536 + (size_t)(i0 + r) * 256 + j0 + c8) =
            *(const uint4*)&q_s[r][c8];
    }
}

// ---------- out = attn @ V^T via MFMA; both i-halves per block (vt staged ONCE) ----------
// grid (CH*8 bh, 8 f0), block 256; writes outb[bh][ns][dl] token-major (coalesced)
__global__ __launch_bounds__(256) void pv_mfma_t(const unsigned short* __restrict__ attn,
    const unsigned short* __restrict__ vt, unsigned short* __restrict__ outb)
{
    __shared__ __align__(16) unsigned short a_s[128][136];
    __shared__ __align__(16) unsigned short b_s[128][136];
    const int bh = blockIdx.x, f0 = blockIdx.y * 128;
    const int tid = threadIdx.x, w = tid >> 6, lane = tid & 63;
    const int wi = w >> 1, wf = w & 1;
    const int lrow = lane & 15, lko = (lane >> 4) * 8;
    const size_t tb = (size_t)bh * 262144;
    f32x4 acc[2][4][4];
    #pragma unroll
    for (int ih = 0; ih < 2; ++ih)
        #pragma unroll
        for (int m = 0; m < 4; ++m)
            #pragma unroll
            for (int n = 0; n < 4; ++n) acc[ih][m][n] = (f32x4)0.f;
    for (int jc = 0; jc < 2; ++jc) {
        __syncthreads();
        // stage b_s[f 128][j 128] via in-LDS transpose from token-major vt (i-independent!)
        for (int idx = tid; idx < 2048; idx += 256) {
            int j = idx & 127, fo = idx >> 7;
            uint4 v = *(const uint4*)(vt + tb + (size_t)(jc * 128 + j) * 1024 + f0 + fo * 8);
            b_s[fo * 8 + 0][j] = (unsigned short)(v.x);
            b_s[fo * 8 + 1][j] = (unsigned short)(v.x >> 16);
            b_s[fo * 8 + 2][j] = (unsigned short)(v.y);
            b_s[fo * 8 + 3][j] = (unsigned short)(v.y >> 16);
            b_s[fo * 8 + 4][j] = (unsigned short)(v.z);
            b_s[fo * 8 + 5][j] = (unsigned short)(v.z >> 16);
            b_s[fo * 8 + 6][j] = (unsigned short)(v.w);
            b_s[fo * 8 + 7][j] = (unsigned short)(v.w >> 16);
        }
        #pragma unroll
        for (int ih = 0; ih < 2; ++ih) {
            if (ih == 1) __syncthreads();   // a_s(ih=0) reads done before restage
            for (int idx = tid; idx < 2048; idx += 256) {
                int r = idx >> 4, c8 = (idx & 15) * 8;
                *(uint4*)&a_s[r][c8] = *(const uint4*)(attn + (size_t)bh * 65536 +
                    (size_t)(ih * 128 + r) * 256 + jc * 128 + c8);
            }
            __syncthreads();
            #pragma unroll
            for (int ks = 0; ks < 4; ++ks) {
                bf16x8 a[4], b[4];
                #pragma unroll
                for (int m = 0; m < 4; ++m) a[m] = *(const bf16x8*)&a_s[wi * 64 + m * 16 + lrow][ks * 32 + lko];
                #pragma unroll
                for (int n = 0; n < 4; ++n) b[n] = *(const bf16x8*)&b_s[wf * 64 + n * 16 + lrow][ks * 32 + lko];
                #pragma unroll
                for (int m = 0; m < 4; ++m)
                    #pragma unroll
                    for (int n = 0; n < 4; ++n)
                        acc[ih][m][n] = __builtin_amdgcn_mfma_f32_16x16x32_bf16(a[m], b[n], acc[ih][m][n], 0, 0, 0);
            }
        }
    }
    #pragma unroll
    for (int ih = 0; ih < 2; ++ih) {
        __syncthreads();
        #pragma unroll
        for (int m = 0; m < 4; ++m)
            #pragma unroll
            for (int n = 0; n < 4; ++n)
                #pragma unroll
                for (int r = 0; r < 4; ++r)
                    a_s[wi * 64 + m * 16 + (lane >> 4) * 4 + r][wf * 64 + n * 16 + lrow] = f2bf(acc[ih][m][n][r]);
        __syncthreads();
        for (int idx = tid; idx < 2048; idx += 256) {
            int r = idx >> 4, c8 = (idx & 15) * 8;
            *(uint4*)(outb + tb + (size_t)(ih * 128 + r) * 1024 + f0 + c8) =
                *(const uint4*)&a_s[r][c8];
        }
    }
}

// ---------- merge conv via MFMA (Cin=512,K=3) + residual -> x2; weights in regs ----------
// staging does the (BH)(NS)(CL) -> (BN)(HC)(LS) rearrange from token-major outb
// grid CH*32, block 256
__global__ __launch_bounds__(256, 3) void merge_mfma(const unsigned short* __restrict__ outb,
    const float* __restrict__ x, const unsigned short* __restrict__ wmg,
    const float* __restrict__ bias, float* __restrict__ x2, int b0)
{
    __shared__ __align__(16) unsigned short ut[130][136];
    const int sl = blockIdx.x, tid = threadIdx.x;
    const int bn = b0 * 32 + sl;
    const int bl = sl >> 5, nn = sl & 31;
    const int w = tid >> 6, lane = tid & 63;
    const int lrow = lane & 15, lko = (lane >> 4) * 8, q4 = lane >> 4;
    if (tid < 128) { ut[0][tid] = 0; ut[129][tid] = 0; }
    f32x4 acc[2][4];
    #pragma unroll
    for (int m = 0; m < 2; ++m)
        #pragma unroll
        for (int n = 0; n < 4; ++n) acc[m][n] = (f32x4)0.f;
    for (int c4 = 0; c4 < 4; ++c4) {
        __syncthreads();
        for (int idx = tid; idx < 2048; idx += 256) {
            int lb = idx & 1, d = (idx >> 1) & 63, s = (idx >> 7) & 7, hh = idx >> 10;
            uint4 v = *(const uint4*)(outb + (size_t)(bl * 8 + c4 * 2 + hh) * 262144 +
                                      (size_t)(nn * 8 + s) * 1024 + d * 16 + lb * 8);
            const unsigned short* vp = (const unsigned short*)&v;
            #pragma unroll
            for (int e = 0; e < 8; ++e) {
                int l = lb * 8 + e;
                ut[1 + l * 8 + s][hh * 64 + d] = vp[e];
            }
        }
        bf16x8 af[3][4][2];
        #pragma unroll
        for (int k = 0; k < 3; ++k)
            #pragma unroll
            for (int kc = 0; kc < 4; ++kc)
                #pragma unroll
                for (int m = 0; m < 2; ++m)
                    af[k][kc][m] = *(const bf16x8*)(wmg + (size_t)k * 32768 +
                        (size_t)((w >> 1) * 32 + m * 16 + lrow) * 512 + c4 * 128 + kc * 32 + lko);
        __syncthreads();
        #pragma unroll
        for (int k = 0; k < 3; ++k) {
            #pragma unroll
            for (int kc = 0; kc < 4; ++kc) {
                bf16x8 b[4];
                #pragma unroll
                for (int n = 0; n < 4; ++n)
                    b[n] = *(const bf16x8*)&ut[(w & 1) * 64 + n * 16 + lrow + k][kc * 32 + lko];
                #pragma unroll
                for (int m = 0; m < 2; ++m)
                    #pragma unroll
                    for (int n = 0; n < 4; ++n)
                        acc[m][n] = __builtin_amdgcn_mfma_f32_16x16x32_bf16(af[k][kc][m], b[n], acc[m][n], 0, 0, 0);
            }
        }
    }
    #pragma unroll
    for (int m = 0; m < 2; ++m) {
        int cb = (w >> 1) * 32 + m * 16 + q4 * 4;
        float bv[4];
        #pragma unroll
        for (int r = 0; r < 4; ++r) bv[r] = bias[cb + r];
        #pragma unroll
        for (int n = 0; n < 4; ++n) {
            int lt = (w & 1) * 64 + n * 16 + lrow;
            #pragma unroll
            for (int r = 0; r < 4; ++r) {
                size_t a = (size_t)bn * 8192 + (size_t)(cb + r) * 128 + lt;
                x2[a] = acc[m][n][r] + bv[r] + x[a];
            }
        }
    }
}

// ---------- ff1 conv via MFMA (Cin=64->256) + swish -> h[bn][lt][256]; weights in regs ----------
// grid (2, 512), block 256
__global__ __launch_bounds__(256, 3) void ff1_mfma(const unsigned short* __restrict__ xnt,
    const unsigned short* __restrict__ wf1, const float* __restrict__ bias,
    unsigned short* __restrict__ hb)
{
    __shared__ __align__(16) unsigned short xt[130][72];
    const int mc = blockIdx.x, bn = blockIdx.y, tid = threadIdx.x;
    const int w = tid >> 6, lane = tid & 63;
    const int lrow = lane & 15, lko = (lane >> 4) * 8, q4 = lane >> 4;
    bf16x8 af[3][2][2];
    #pragma unroll
    for (int k = 0; k < 3; ++k)
        #pragma unroll
        for (int kc = 0; kc < 2; ++kc)
            #pragma unroll
            for (int m = 0; m < 2; ++m)
                af[k][kc][m] = *(const bf16x8*)(wf1 + (size_t)k * 16384 +
                    (size_t)(mc * 128 + w * 32 + m * 16 + lrow) * 64 + kc * 32 + lko);
    for (int idx = tid; idx < 1040; idx += 256)
        *(uint4*)&xt[idx >> 3][(idx & 7) * 8] = *(const uint4*)(xnt + (size_t)bn * 8320 + idx * 8);
    __syncthreads();
    f32x4 acc[2][8];
    #pragma unroll
    for (int m = 0; m < 2; ++m)
        #pragma unroll
        for (int n = 0; n < 8; ++n) acc[m][n] = (f32x4)0.f;
    #pragma unroll
    for (int k = 0; k < 3; ++k) {
        #pragma unroll
        for (int kc = 0; kc < 2; ++kc) {
            #pragma unroll
            for (int n = 0; n < 8; ++n) {
                bf16x8 b = *(const bf16x8*)&xt[n * 16 + lrow + k][kc * 32 + lko];
                acc[0][n] = __builtin_amdgcn_mfma_f32_16x16x32_bf16(af[k][kc][0], b, acc[0][n], 0, 0, 0);
                acc[1][n] = __builtin_amdgcn_mfma_f32_16x16x32_bf16(af[k][kc][1], b, acc[1][n], 0, 0, 0);
            }
        }
    }
    #pragma unroll
    for (int m = 0; m < 2; ++m) {
        int rb = w * 32 + m * 16 + q4 * 4;
        float bv[4];
        #pragma unroll
        for (int r = 0; r < 4; ++r) bv[r] = bias[mc * 128 + rb + r];
        #pragma unroll
        for (int n = 0; n < 8; ++n) {
            int lt = n * 16 + lrow;
            float sws[4];
            #pragma unroll
            for (int r = 0; r < 4; ++r) {
                float t = acc[m][n][r] + bv[r];
                sws[r] = t / (1.f + __expf(-t));
            }
            uint2 o = {pack2(sws[0], sws[1]), pack2(sws[2], sws[3])};
            *(uint2*)(hb + (size_t)bn * 32768 + (size_t)lt * 256 + mc * 128 + rb) = o;
        }
    }
}

// ---------- ff2 conv via MFMA (Cin=256->64) + residual -> y; weights in regs ----------
// grid 512, block 256
__global__ __launch_bounds__(256, 3) void ff2_mfma(const unsigned short* __restrict__ hb,
    const float* __restrict__ x2, const unsigned short* __restrict__ wf2,
    const float* __restrict__ bias, float* __restrict__ y)
{
    __shared__ __align__(16) unsigned short ut[130][136];
    const int bn = blockIdx.x, tid = threadIdx.x;
    const int w = tid >> 6, lane = tid & 63;
    const int lrow = lane & 15, lko = (lane >> 4) * 8, q4 = lane >> 4;
    if (tid < 128) { ut[0][tid] = 0; ut[129][tid] = 0; }
    f32x4 acc[2][4];
    #pragma unroll
    for (int m = 0; m < 2; ++m)
        #pragma unroll
        for (int n = 0; n < 4; ++n) acc[m][n] = (f32x4)0.f;
    for (int c2 = 0; c2 < 2; ++c2) {
        __syncthreads();
        for (int idx = tid; idx < 2048; idx += 256) {
            int lt = idx >> 4, ci8 = (idx & 15) * 8;
            *(uint4*)&ut[1 + lt][ci8] =
                *(const uint4*)(hb + (size_t)bn * 32768 + (size_t)lt * 256 + c2 * 128 + ci8);
        }
        bf16x8 af[3][4][2];
        #pragma unroll
        for (int k = 0; k < 3; ++k)
            #pragma unroll
            for (int kc = 0; kc < 4; ++kc)
                #pragma unroll
                for (int m = 0; m < 2; ++m)
                    af[k][kc][m] = *(const bf16x8*)(wf2 + (size_t)k * 16384 +
                        (size_t)((w >> 1) * 32 + m * 16 + lrow) * 256 + c2 * 128 + kc * 32 + lko);
        __syncthreads();
        #pragma unroll
        for (int k = 0; k < 3; ++k) {
            #pragma unroll
            for (int kc = 0; kc < 4; ++kc) {
                bf16x8 b[4];
                #pragma unroll
                for (int n = 0; n < 4; ++n)
                    b[n] = *(const bf16x8*)&ut[(w & 1) * 64 + n * 16 + lrow + k][kc * 32 + lko];
                #pragma unroll
                for (int m = 0; m < 2; ++m)
                    #pragma unroll
                    for (int n = 0; n < 4; ++n)
                        acc[m][n] = __builtin_amdgcn_mfma_f32_16x16x32_bf16(af[k][kc][m], b[n], acc[m][n], 0, 0, 0);
            }
        }
    }
    #pragma unroll
    for (int m = 0; m < 2; ++m) {
        int cb = (w >> 1) * 32 + m * 16 + q4 * 4;
        float bv[4];
        #pragma unroll
        for (int r = 0; r < 4; ++r) bv[r] = bias[cb + r];
        #pragma unroll
        for (int n = 0; n < 4; ++n) {
            int lt = (w & 1) * 64 + n * 16 + lrow;
            #pragma unroll
            for (int r = 0; r < 4; ++r) {
                size_t a = (size_t)bn * 8192 + (size_t)(cb + r) * 128 + lt;
                y[a] = acc[m][n][r] + bv[r] + x2[a];
            }
        }
    }
}

// ---------- launch ----------
extern "C" void kernel_launch(void* const* d_in, const int* in_sizes, int n_in,
                              void* d_out, int out_size, void* d_ws, size_t ws_size,
                              hipStream_t stream) {
    (void)in_sizes; (void)n_in; (void)out_size;
    const float* x     = (const float*)d_in[0];
    const float* gn1_g = (const float*)d_in[1];
    const float* gn1_b = (const float*)d_in[2];
    const float* w_qkv = (const float*)d_in[3];
    const float* b_qkv = (const float*)d_in[4];
    const float* w_mg  = (const float*)d_in[5];
    const float* b_mg  = (const float*)d_in[6];
    const float* gn2_g = (const float*)d_in[7];
    const float* gn2_b = (const float*)d_in[8];
    const float* w_f1  = (const float*)d_in[9];
    const float* b_f1  = (const float*)d_in[10];
    const float* w_f2  = (const float*)d_in[11];
    const float* b_f2  = (const float*)d_in[12];
    float* y = (float*)d_out;

    char* ws = (char*)d_ws;
    const size_t OFF_NQ  = 0;             // <=128 KB
    const size_t OFF_NK  = 131072;
    const size_t OFF_WQ  = 262144;        // 589,824 B
    const size_t OFF_WMG = 917504;        // 196,608 B
    const size_t OFF_WF1 = 1114112;       // 98,304 B
    const size_t OFF_WF2 = 1212416;       // 98,304 B
    const size_t OFF_X2  = 1310720;       // 16.78 MB -> ends 18,087,936
    const size_t OFF_XNT = 18087936;      // 8,519,680 -> ends 26,607,616
    const size_t OFF_CHUNK = 26607616;
    const size_t H_BYTES = 33554432;

    // per-chunk regions: Q, K, VT, ATTN; OUTB aliases Q (dead after attnw)
    int CH = 1;
    {
        const int cands[5] = {16, 8, 4, 2, 1};
        for (int ci = 0; ci < 5; ++ci) {
            int c = cands[ci];
            size_t qsz = (size_t)c * 4194304;
            size_t asz = (size_t)c * 1048576;
            size_t body = 3 * qsz + asz;
            if (body < H_BYTES) body = H_BYTES;
            if (OFF_CHUNK + body <= ws_size) { CH = c; break; }
        }
    }
    const size_t QSZ = (size_t)CH * 4194304;
    const size_t OFF_Q  = OFF_CHUNK;
    const size_t OFF_K  = OFF_Q + QSZ;
    const size_t OFF_VT = OFF_K + QSZ;
    const size_t OFF_AT = OFF_VT + QSZ;

    float* nqp = (float*)(ws + OFF_NQ);
    float* nkp = (float*)(ws + OFF_NK);
    unsigned short* wqb  = (unsigned short*)(ws + OFF_WQ);
    unsigned short* wmgb = (unsigned short*)(ws + OFF_WMG);
    unsigned short* wf1b = (unsigned short*)(ws + OFF_WF1);
    unsigned short* wf2b = (unsigned short*)(ws + OFF_WF2);
    float* x2  = (float*)(ws + OFF_X2);
    unsigned short* xnt  = (unsigned short*)(ws + OFF_XNT);
    unsigned short* qb   = (unsigned short*)(ws + OFF_Q);
    unsigned short* kb   = (unsigned short*)(ws + OFF_K);
    unsigned short* vtb  = (unsigned short*)(ws + OFF_VT);
    unsigned short* attn = (unsigned short*)(ws + OFF_AT);
    unsigned short* outb = (unsigned short*)(ws + OFF_Q);      // Q dead after attnw
    unsigned short* hbuf = (unsigned short*)(ws + OFF_CHUNK);  // after loop

    gnx_kernel<<<512, 256, 0, stream>>>(x, gn1_g, gn1_b, xnt);
    prep_w_kernel<<<384, 256, 0, stream>>>(w_qkv, wqb, 98304);
    prep_w_kernel<<<128, 256, 0, stream>>>(w_mg,  wmgb, 32768);
    prep_w_kernel<<<64,  256, 0, stream>>>(w_f1,  wf1b, 16384);
    prep_w_kernel<<<64,  256, 0, stream>>>(w_f2,  wf2b, 16384);
    const int nch = 16 / CH;
    for (int cidx = 0; cidx < nch; ++cidx) {
        int b0 = cidx * CH;
        conv_qkv_mfma<<<dim3(CH * 32, 12), 256, 0, stream>>>(xnt, wqb, b_qkv, qb, kb, vtb, nqp, nkp, b0);
        attnw_mfma<<<dim3(CH * 8, 2, 2), 256, 0, stream>>>(qb, kb, nqp, nkp, attn);
        pv_mfma_t<<<dim3(CH * 8, 8), 256, 0, stream>>>(attn, vtb, outb);
        merge_mfma<<<CH * 32, 256, 0, stream>>>(outb, x, wmgb, b_mg, x2, b0);
    }
    gnx_kernel<<<512, 256, 0, stream>>>(x2, gn2_g, gn2_b, xnt);
    ff1_mfma<<<dim3(2, 512), 256, 0, stream>>>(xnt, wf1b, b_f1, hbuf);
    ff2_mfma<<<512, 256, 0, stream>>>(hbuf, x2, wf2b, b_f2, y);
}

// Round 18
// 274.577 us; speedup vs baseline: 1.0445x; 1.0445x over previous
//
#include <hip/hip_runtime.h>
#include <hip/hip_bf16.h>

#define DEV __device__ __forceinline__

typedef __attribute__((ext_vector_type(8))) __bf16 bf16x8;
typedef __attribute__((ext_vector_type(4))) float f32x4;

// ---------- bf16 helpers (bit-level) ----------
DEV float bfu(unsigned short u) { return __uint_as_float((unsigned int)u << 16); }
DEV unsigned short f2bf(float f) {
    union { float f; unsigned int u; } cv; cv.f = f;
    unsigned int u = cv.u;
    unsigned int r = (u + 0x7fffu + ((u >> 16) & 1u)) >> 16;  // RNE
    return (unsigned short)r;
}
DEV unsigned int pack2(float a, float b) {
    return (unsigned int)f2bf(a) | ((unsigned int)f2bf(b) << 16);
}
// bank-conflict swizzle for scalar-accessed ct tile (word-granular XOR)
DEV int cs(int row, int col) { return col ^ ((row & 15) << 1); }

// dims: B=16 N=32 D=64 H=8 S=8 LT=128 DE=256 L=16
// BN=512 BH=128 NS=256 DL=1024 DQKV=1536

// ---------- fused GroupNorm stats + normalize + transpose: x -> xnt[bn][130][64] ----------
// grid 512, block 256
__global__ __launch_bounds__(256) void gnx_kernel(const float* __restrict__ src,
    const float* __restrict__ gamma, const float* __restrict__ beta,
    unsigned short* __restrict__ xnt)
{
    __shared__ __align__(16) float sx[64][133];
    __shared__ float gsum[8], gsq[8], la[64], lb[64];
    const int s = blockIdx.x, tid = threadIdx.x;
    for (int idx = tid; idx < 8192; idx += 256) {
        int c = idx >> 7, lt = idx & 127;
        sx[c][lt] = src[(size_t)s * 8192 + idx];
    }
    __syncthreads();
    const int g = tid >> 5, il = tid & 31;
    float sm = 0.f, sq = 0.f;
    #pragma unroll
    for (int m = 0; m < 32; ++m) {
        int e = il + m * 32;
        float v = sx[g * 8 + (e >> 7)][e & 127];
        sm += v; sq += v * v;
    }
    #pragma unroll
    for (int m = 16; m; m >>= 1) { sm += __shfl_xor(sm, m); sq += __shfl_xor(sq, m); }
    if (il == 0) { gsum[g] = sm; gsq[g] = sq; }
    __syncthreads();
    if (tid < 64) {
        int gg = tid >> 3;
        float mu = gsum[gg] * (1.f / 1024.f);
        float var = gsq[gg] * (1.f / 1024.f) - mu * mu;
        float a = gamma[tid] * rsqrtf(var + 1e-5f);
        la[tid] = a; lb[tid] = beta[tid] - mu * a;
    }
    __syncthreads();
    for (int idx = tid; idx < 8320; idx += 256) {
        int row = idx >> 6, c = idx & 63;
        float v = 0.f;
        if (row >= 1 && row <= 128) v = sx[c][row - 1] * la[c] + lb[c];
        xnt[(size_t)s * 8320 + idx] = f2bf(v);
    }
}

// ---------- generic weight prep ----------
__global__ __launch_bounds__(256) void prep_w_kernel(const float* __restrict__ w,
    unsigned short* __restrict__ dst, int n)
{
    int i = blockIdx.x * 256 + threadIdx.x;
    if (i < n) {
        #pragma unroll
        for (int k = 0; k < 3; ++k)
            dst[k * n + i] = f2bf(w[(size_t)i * 3 + k]);
    }
}

// ---------- QKV conv via MFMA; q/k/v token-major coalesced; fused q/k norms ----------
// grid (CH*32 scenes, 12 chunks) -> same-scene blocks co-locate on one XCD
__global__ __launch_bounds__(256, 3) void conv_qkv_mfma(
    const unsigned short* __restrict__ xnt,
    const unsigned short* __restrict__ wq, const float* __restrict__ bias,
    unsigned short* __restrict__ qb, unsigned short* __restrict__ kb,
    unsigned short* __restrict__ vt, float* __restrict__ nq, float* __restrict__ nk,
    int b0)
{
    __shared__ __align__(16) char smem[34816];
    unsigned short (*xt)[72]  = (unsigned short(*)[72])smem;   // [130][72]
    unsigned short (*ct)[136] = (unsigned short(*)[136])smem;  // [128][136] overlay

    const int sl = blockIdx.x, mc = blockIdx.y, tid = threadIdx.x;
    const int bn = b0 * 32 + sl;
    const int w = tid >> 6, lane = tid & 63;
    const int lrow = lane & 15, lko = (lane >> 4) * 8, q4 = lane >> 4;

    bf16x8 af[3][2][2];
    #pragma unroll
    for (int k = 0; k < 3; ++k)
        #pragma unroll
        for (int kc = 0; kc < 2; ++kc)
            #pragma unroll
            for (int m = 0; m < 2; ++m)
                af[k][kc][m] = *(const bf16x8*)(wq + (size_t)k * 98304 +
                    (size_t)(mc * 128 + w * 32 + m * 16 + lrow) * 64 + kc * 32 + lko);

    for (int idx = tid; idx < 1040; idx += 256)
        *(uint4*)&xt[idx >> 3][(idx & 7) * 8] = *(const uint4*)(xnt + (size_t)bn * 8320 + idx * 8);
    __syncthreads();

    f32x4 acc[2][8];
    #pragma unroll
    for (int m = 0; m < 2; ++m)
        #pragma unroll
        for (int n = 0; n < 8; ++n) acc[m][n] = (f32x4)0.f;
    #pragma unroll
    for (int k = 0; k < 3; ++k) {
        #pragma unroll
        for (int kc = 0; kc < 2; ++kc) {
            #pragma unroll
            for (int n = 0; n < 8; ++n) {
                bf16x8 b = *(const bf16x8*)&xt[n * 16 + lrow + k][kc * 32 + lko];
                acc[0][n] = __builtin_amdgcn_mfma_f32_16x16x32_bf16(af[k][kc][0], b, acc[0][n], 0, 0, 0);
                acc[1][n] = __builtin_amdgcn_mfma_f32_16x16x32_bf16(af[k][kc][1], b, acc[1][n], 0, 0, 0);
            }
        }
    }
    __syncthreads();   // xt dead; reuse as ct
    const int c0 = mc * 128;
    float bv[2][4];
    #pragma unroll
    for (int m = 0; m < 2; ++m)
        #pragma unroll
        for (int r = 0; r < 4; ++r)
            bv[m][r] = bias[c0 + w * 32 + m * 16 + q4 * 4 + r];
    #pragma unroll
    for (int m = 0; m < 2; ++m)
        #pragma unroll
        for (int n = 0; n < 8; ++n)
            #pragma unroll
            for (int r = 0; r < 4; ++r) {
                int row = w * 32 + m * 16 + q4 * 4 + r;
                ct[row][cs(row, n * 16 + lrow)] = f2bf(acc[m][n][r] + bv[m][r]);
            }
    __syncthreads();
    const int t = mc >> 2, h_base = (mc & 3) * 2;
    const int bl = sl >> 5, n_tr = sl & 31;
    unsigned short* dst = (t == 0) ? qb : ((t == 1) ? kb : vt);
    for (int idx = tid; idx < 2048; idx += 256) {
        int lb = idx & 1;
        int d  = (idx >> 1) & 63;
        int s  = (idx >> 7) & 7;
        int hl = idx >> 10;
        int row = hl * 64 + d;
        unsigned int uu[4];
        #pragma unroll
        for (int e2 = 0; e2 < 4; ++e2) {
            unsigned short w0 = ct[row][cs(row, (lb * 8 + e2 * 2) * 8 + s)];
            unsigned short w1 = ct[row][cs(row, (lb * 8 + e2 * 2 + 1) * 8 + s)];
            uu[e2] = (unsigned int)w0 | ((unsigned int)w1 << 16);
        }
        uint4 o = {uu[0], uu[1], uu[2], uu[3]};
        size_t a = ((size_t)((bl * 8 + h_base + hl) * 256 + n_tr * 8 + s)) * 1024 + d * 16 + lb * 8;
        *(uint4*)(dst + a) = o;
    }
    if (t < 2) {
        float* ndst = t ? nk : nq;
        const int tk = tid >> 4, l = tid & 15;
        const int hl = tk >> 3, sS = tk & 7;
        float s2 = 0.f;
        for (int d = 0; d < 64; ++d) {
            int row = hl * 64 + d;
            float v = bfu(ct[row][cs(row, l * 8 + sS)]);
            s2 = fmaf(v, v, s2);
        }
        #pragma unroll
        for (int m = 8; m; m >>= 1) s2 += __shfl_xor(s2, m);
        if (l == 0)
            ndst[(bl * 8 + h_base + hl) * 256 + n_tr * 8 + sS] = s2;
    }
}

// ---------- attn weights via MFMA: S=QK^T, W=rsqrt(nq+nk-2S) ----------
// grid (CH*8 bh, 2 i0, 2 j0) -> same-bh blocks co-locate on one XCD
__global__ __launch_bounds__(256) void attnw_mfma(const unsigned short* __restrict__ qb,
    const unsigned short* __restrict__ kb, const float* __restrict__ nq,
    const float* __restrict__ nk, unsigned short* __restrict__ attn)
{
    __shared__ __align__(16) unsigned short q_s[128][136];
    __shared__ __align__(16) unsigned short k_s[128][136];
    const int bh = blockIdx.x, i0 = blockIdx.y * 128, j0 = blockIdx.z * 128;
    const int tid = threadIdx.x, w = tid >> 6, lane = tid & 63;
    const int wi = w >> 1, wj = w & 1;
    const int lrow = lane & 15, lko = (lane >> 4) * 8;
    f32x4 acc[4][4];
    #pragma unroll
    for (int m = 0; m < 4; ++m)
        #pragma unroll
        for (int n = 0; n < 4; ++n) acc[m][n] = (f32x4)0.f;
    const size_t tb = (size_t)bh * 262144;
    for (int fc = 0; fc < 8; ++fc) {
        __syncthreads();
        for (int idx = tid; idx < 2048; idx += 256) {
            int r = idx >> 4, c8 = (idx & 15) * 8;
            *(uint4*)&q_s[r][c8] = *(const uint4*)(qb + tb + (size_t)(i0 + r) * 1024 + fc * 128 + c8);
            *(uint4*)&k_s[r][c8] = *(const uint4*)(kb + tb + (size_t)(j0 + r) * 1024 + fc * 128 + c8);
        }
        __syncthreads();
        #pragma unroll
        for (int ks = 0; ks < 4; ++ks) {
            bf16x8 a[4], b[4];
            #pragma unroll
            for (int m = 0; m < 4; ++m) a[m] = *(const bf16x8*)&q_s[wi * 64 + m * 16 + lrow][ks * 32 + lko];
            #pragma unroll
            for (int n = 0; n < 4; ++n) b[n] = *(const bf16x8*)&k_s[wj * 64 + n * 16 + lrow][ks * 32 + lko];
            #pragma unroll
            for (int m = 0; m < 4; ++m)
                #pragma unroll
                for (int n = 0; n < 4; ++n)
                    acc[m][n] = __builtin_amdgcn_mfma_f32_16x16x32_bf16(a[m], b[n], acc[m][n], 0, 0, 0);
        }
    }
    float nqv[4][4], nkv[4];
    #pragma unroll
    for (int m = 0; m < 4; ++m)
        #pragma unroll
        for (int r = 0; r < 4; ++r)
            nqv[m][r] = nq[bh * 256 + i0 + wi * 64 + m * 16 + (lane >> 4) * 4 + r];
    #pragma unroll
    for (int n = 0; n < 4; ++n)
        nkv[n] = nk[bh * 256 + j0 + wj * 64 + n * 16 + lrow];
    __syncthreads();
    #pragma unroll
    for (int m = 0; m < 4; ++m)
        #pragma unroll
        for (int n = 0; n < 4; ++n)
            #pragma unroll
            for (int r = 0; r < 4; ++r) {
                float sq = nqv[m][r] + nkv[n] - 2.f * acc[m][n][r];
                q_s[wi * 64 + m * 16 + (lane >> 4) * 4 + r][wj * 64 + n * 16 + lrow] =
                    f2bf(rsqrtf(fmaxf(sq, 1e-12f)));
            }
    __syncthreads();
    for (int idx = tid; idx < 2048; idx += 256) {
        int r = idx >> 4, c8 = (idx & 15) * 8;
        *(uint4*)(attn + (size_t)bh * 65536 + (size_t)(i0 + r) * 256 + j0 + c8) =
            *(const uint4*)&q_s[r][c8];
    }
}

// ---------- out = attn @ V^T via MFMA; V staged token-major + in-LDS transpose ----------
// grid (CH*8 bh, 2 i-halves, 8 f0) -> same-bh blocks co-locate on one XCD
__global__ __launch_bounds__(256) void pv_mfma_t(const unsigned short* __restrict__ attn,
    const unsigned short* __restrict__ vt, unsigned short* __restrict__ outb)
{
    __shared__ __align__(16) unsigned short a_s[128][136];
    __shared__ __align__(16) unsigned short b_s[128][136];
    const int bh = blockIdx.x, i0 = blockIdx.y * 128, f0 = blockIdx.z * 128;
    const int tid = threadIdx.x, w = tid >> 6, lane = tid & 63;
    const int wi = w >> 1, wf = w & 1;
    const int lrow = lane & 15, lko = (lane >> 4) * 8;
    const size_t tb = (size_t)bh * 262144;
    f32x4 acc[4][4];
    #pragma unroll
    for (int m = 0; m < 4; ++m)
        #pragma unroll
        for (int n = 0; n < 4; ++n) acc[m][n] = (f32x4)0.f;
    for (int jc = 0; jc < 2; ++jc) {
        __syncthreads();
        for (int idx = tid; idx < 2048; idx += 256) {
            int r = idx >> 4, c8 = (idx & 15) * 8;
            *(uint4*)&a_s[r][c8] = *(const uint4*)(attn + (size_t)bh * 65536 + (size_t)(i0 + r) * 256 + jc * 128 + c8);
        }
        // stage b_s[f 128][j 128] via in-LDS transpose from token-major vt
        for (int idx = tid; idx < 2048; idx += 256) {
            int j = idx & 127, fo = idx >> 7;
            uint4 v = *(const uint4*)(vt + tb + (size_t)(jc * 128 + j) * 1024 + f0 + fo * 8);
            b_s[fo * 8 + 0][j] = (unsigned short)(v.x);
            b_s[fo * 8 + 1][j] = (unsigned short)(v.x >> 16);
            b_s[fo * 8 + 2][j] = (unsigned short)(v.y);
            b_s[fo * 8 + 3][j] = (unsigned short)(v.y >> 16);
            b_s[fo * 8 + 4][j] = (unsigned short)(v.z);
            b_s[fo * 8 + 5][j] = (unsigned short)(v.z >> 16);
            b_s[fo * 8 + 6][j] = (unsigned short)(v.w);
            b_s[fo * 8 + 7][j] = (unsigned short)(v.w >> 16);
        }
        __syncthreads();
        #pragma unroll
        for (int ks = 0; ks < 4; ++ks) {
            bf16x8 a[4], b[4];
            #pragma unroll
            for (int m = 0; m < 4; ++m) a[m] = *(const bf16x8*)&a_s[wi * 64 + m * 16 + lrow][ks * 32 + lko];
            #pragma unroll
            for (int n = 0; n < 4; ++n) b[n] = *(const bf16x8*)&b_s[wf * 64 + n * 16 + lrow][ks * 32 + lko];
            #pragma unroll
            for (int m = 0; m < 4; ++m)
                #pragma unroll
                for (int n = 0; n < 4; ++n)
                    acc[m][n] = __builtin_amdgcn_mfma_f32_16x16x32_bf16(a[m], b[n], acc[m][n], 0, 0, 0);
        }
    }
    __syncthreads();
    #pragma unroll
    for (int m = 0; m < 4; ++m)
        #pragma unroll
        for (int n = 0; n < 4; ++n)
            #pragma unroll
            for (int r = 0; r < 4; ++r)
                a_s[wi * 64 + m * 16 + (lane >> 4) * 4 + r][wf * 64 + n * 16 + lrow] = f2bf(acc[m][n][r]);
    __syncthreads();
    // token-major coalesced store: outb[bh][i0+r][f0 + col]
    for (int idx = tid; idx < 2048; idx += 256) {
        int r = idx >> 4, c8 = (idx & 15) * 8;
        *(uint4*)(outb + tb + (size_t)(i0 + r) * 1024 + f0 + c8) =
            *(const uint4*)&a_s[r][c8];
    }
}

// ---------- merge conv via MFMA (Cin=512,K=3) + residual -> x2; weights in regs ----------
// staging does the (BH)(NS)(CL) -> (BN)(HC)(LS) rearrange from token-major outb
// grid CH*32, block 256
__global__ __launch_bounds__(256, 3) void merge_mfma(const unsigned short* __restrict__ outb,
    const float* __restrict__ x, const unsigned short* __restrict__ wmg,
    const float* __restrict__ bias, float* __restrict__ x2, int b0)
{
    __shared__ __align__(16) unsigned short ut[130][136];
    const int sl = blockIdx.x, tid = threadIdx.x;
    const int bn = b0 * 32 + sl;
    const int bl = sl >> 5, nn = sl & 31;
    const int w = tid >> 6, lane = tid & 63;
    const int lrow = lane & 15, lko = (lane >> 4) * 8, q4 = lane >> 4;
    if (tid < 128) { ut[0][tid] = 0; ut[129][tid] = 0; }
    f32x4 acc[2][4];
    #pragma unroll
    for (int m = 0; m < 2; ++m)
        #pragma unroll
        for (int n = 0; n < 4; ++n) acc[m][n] = (f32x4)0.f;
    for (int c4 = 0; c4 < 4; ++c4) {
        __syncthreads();
        for (int idx = tid; idx < 2048; idx += 256) {
            int lb = idx & 1, d = (idx >> 1) & 63, s = (idx >> 7) & 7, hh = idx >> 10;
            uint4 v = *(const uint4*)(outb + (size_t)(bl * 8 + c4 * 2 + hh) * 262144 +
                                      (size_t)(nn * 8 + s) * 1024 + d * 16 + lb * 8);
            const unsigned short* vp = (const unsigned short*)&v;
            #pragma unroll
            for (int e = 0; e < 8; ++e) {
                int l = lb * 8 + e;
                ut[1 + l * 8 + s][hh * 64 + d] = vp[e];
            }
        }
        bf16x8 af[3][4][2];
        #pragma unroll
        for (int k = 0; k < 3; ++k)
            #pragma unroll
            for (int kc = 0; kc < 4; ++kc)
                #pragma unroll
                for (int m = 0; m < 2; ++m)
                    af[k][kc][m] = *(const bf16x8*)(wmg + (size_t)k * 32768 +
                        (size_t)((w >> 1) * 32 + m * 16 + lrow) * 512 + c4 * 128 + kc * 32 + lko);
        __syncthreads();
        #pragma unroll
        for (int k = 0; k < 3; ++k) {
            #pragma unroll
            for (int kc = 0; kc < 4; ++kc) {
                bf16x8 b[4];
                #pragma unroll
                for (int n = 0; n < 4; ++n)
                    b[n] = *(const bf16x8*)&ut[(w & 1) * 64 + n * 16 + lrow + k][kc * 32 + lko];
                #pragma unroll
                for (int m = 0; m < 2; ++m)
                    #pragma unroll
                    for (int n = 0; n < 4; ++n)
                        acc[m][n] = __builtin_amdgcn_mfma_f32_16x16x32_bf16(af[k][kc][m], b[n], acc[m][n], 0, 0, 0);
            }
        }
    }
    #pragma unroll
    for (int m = 0; m < 2; ++m) {
        int cb = (w >> 1) * 32 + m * 16 + q4 * 4;
        float bv[4];
        #pragma unroll
        for (int r = 0; r < 4; ++r) bv[r] = bias[cb + r];
        #pragma unroll
        for (int n = 0; n < 4; ++n) {
            int lt = (w & 1) * 64 + n * 16 + lrow;
            #pragma unroll
            for (int r = 0; r < 4; ++r) {
                size_t a = (size_t)bn * 8192 + (size_t)(cb + r) * 128 + lt;
                x2[a] = acc[m][n][r] + bv[r] + x[a];
            }
        }
    }
}

// ---------- ff1 conv via MFMA (Cin=64->256) + swish -> h[bn][lt][256]; weights in regs ----------
// grid (2, 512), block 256
__global__ __launch_bounds__(256, 3) void ff1_mfma(const unsigned short* __restrict__ xnt,
    const unsigned short* __restrict__ wf1, const float* __restrict__ bias,
    unsigned short* __restrict__ hb)
{
    __shared__ __align__(16) unsigned short xt[130][72];
    const int mc = blockIdx.x, bn = blockIdx.y, tid = threadIdx.x;
    const int w = tid >> 6, lane = tid & 63;
    const int lrow = lane & 15, lko = (lane >> 4) * 8, q4 = lane >> 4;
    bf16x8 af[3][2][2];
    #pragma unroll
    for (int k = 0; k < 3; ++k)
        #pragma unroll
        for (int kc = 0; kc < 2; ++kc)
            #pragma unroll
            for (int m = 0; m < 2; ++m)
                af[k][kc][m] = *(const bf16x8*)(wf1 + (size_t)k * 16384 +
                    (size_t)(mc * 128 + w * 32 + m * 16 + lrow) * 64 + kc * 32 + lko);
    for (int idx = tid; idx < 1040; idx += 256)
        *(uint4*)&xt[idx >> 3][(idx & 7) * 8] = *(const uint4*)(xnt + (size_t)bn * 8320 + idx * 8);
    __syncthreads();
    f32x4 acc[2][8];
    #pragma unroll
    for (int m = 0; m < 2; ++m)
        #pragma unroll
        for (int n = 0; n < 8; ++n) acc[m][n] = (f32x4)0.f;
    #pragma unroll
    for (int k = 0; k < 3; ++k) {
        #pragma unroll
        for (int kc = 0; kc < 2; ++kc) {
            #pragma unroll
            for (int n = 0; n < 8; ++n) {
                bf16x8 b = *(const bf16x8*)&xt[n * 16 + lrow + k][kc * 32 + lko];
                acc[0][n] = __builtin_amdgcn_mfma_f32_16x16x32_bf16(af[k][kc][0], b, acc[0][n], 0, 0, 0);
                acc[1][n] = __builtin_amdgcn_mfma_f32_16x16x32_bf16(af[k][kc][1], b, acc[1][n], 0, 0, 0);
            }
        }
    }
    #pragma unroll
    for (int m = 0; m < 2; ++m) {
        int rb = w * 32 + m * 16 + q4 * 4;
        float bv[4];
        #pragma unroll
        for (int r = 0; r < 4; ++r) bv[r] = bias[mc * 128 + rb + r];
        #pragma unroll
        for (int n = 0; n < 8; ++n) {
            int lt = n * 16 + lrow;
            float sws[4];
            #pragma unroll
            for (int r = 0; r < 4; ++r) {
                float t = acc[m][n][r] + bv[r];
                sws[r] = t / (1.f + __expf(-t));
            }
            uint2 o = {pack2(sws[0], sws[1]), pack2(sws[2], sws[3])};
            *(uint2*)(hb + (size_t)bn * 32768 + (size_t)lt * 256 + mc * 128 + rb) = o;
        }
    }
}

// ---------- ff2 conv via MFMA (Cin=256->64) + residual -> y; weights in regs ----------
// grid 512, block 256
__global__ __launch_bounds__(256, 3) void ff2_mfma(const unsigned short* __restrict__ hb,
    const float* __restrict__ x2, const unsigned short* __restrict__ wf2,
    const float* __restrict__ bias, float* __restrict__ y)
{
    __shared__ __align__(16) unsigned short ut[130][136];
    const int bn = blockIdx.x, tid = threadIdx.x;
    const int w = tid >> 6, lane = tid & 63;
    const int lrow = lane & 15, lko = (lane >> 4) * 8, q4 = lane >> 4;
    if (tid < 128) { ut[0][tid] = 0; ut[129][tid] = 0; }
    f32x4 acc[2][4];
    #pragma unroll
    for (int m = 0; m < 2; ++m)
        #pragma unroll
        for (int n = 0; n < 4; ++n) acc[m][n] = (f32x4)0.f;
    for (int c2 = 0; c2 < 2; ++c2) {
        __syncthreads();
        for (int idx = tid; idx < 2048; idx += 256) {
            int lt = idx >> 4, ci8 = (idx & 15) * 8;
            *(uint4*)&ut[1 + lt][ci8] =
                *(const uint4*)(hb + (size_t)bn * 32768 + (size_t)lt * 256 + c2 * 128 + ci8);
        }
        bf16x8 af[3][4][2];
        #pragma unroll
        for (int k = 0; k < 3; ++k)
            #pragma unroll
            for (int kc = 0; kc < 4; ++kc)
                #pragma unroll
                for (int m = 0; m < 2; ++m)
                    af[k][kc][m] = *(const bf16x8*)(wf2 + (size_t)k * 16384 +
                        (size_t)((w >> 1) * 32 + m * 16 + lrow) * 256 + c2 * 128 + kc * 32 + lko);
        __syncthreads();
        #pragma unroll
        for (int k = 0; k < 3; ++k) {
            #pragma unroll
            for (int kc = 0; kc < 4; ++kc) {
                bf16x8 b[4];
                #pragma unroll
                for (int n = 0; n < 4; ++n)
                    b[n] = *(const bf16x8*)&ut[(w & 1) * 64 + n * 16 + lrow + k][kc * 32 + lko];
                #pragma unroll
                for (int m = 0; m < 2; ++m)
                    #pragma unroll
                    for (int n = 0; n < 4; ++n)
                        acc[m][n] = __builtin_amdgcn_mfma_f32_16x16x32_bf16(af[k][kc][m], b[n], acc[m][n], 0, 0, 0);
            }
        }
    }
    #pragma unroll
    for (int m = 0; m < 2; ++m) {
        int cb = (w >> 1) * 32 + m * 16 + q4 * 4;
        float bv[4];
        #pragma unroll
        for (int r = 0; r < 4; ++r) bv[r] = bias[cb + r];
        #pragma unroll
        for (int n = 0; n < 4; ++n) {
            int lt = (w & 1) * 64 + n * 16 + lrow;
            #pragma unroll
            for (int r = 0; r < 4; ++r) {
                size_t a = (size_t)bn * 8192 + (size_t)(cb + r) * 128 + lt;
                y[a] = acc[m][n][r] + bv[r] + x2[a];
            }
        }
    }
}

// ---------- launch ----------
extern "C" void kernel_launch(void* const* d_in, const int* in_sizes, int n_in,
                              void* d_out, int out_size, void* d_ws, size_t ws_size,
                              hipStream_t stream) {
    (void)in_sizes; (void)n_in; (void)out_size;
    const float* x     = (const float*)d_in[0];
    const float* gn1_g = (const float*)d_in[1];
    const float* gn1_b = (const float*)d_in[2];
    const float* w_qkv = (const float*)d_in[3];
    const float* b_qkv = (const float*)d_in[4];
    const float* w_mg  = (const float*)d_in[5];
    const float* b_mg  = (const float*)d_in[6];
    const float* gn2_g = (const float*)d_in[7];
    const float* gn2_b = (const float*)d_in[8];
    const float* w_f1  = (const float*)d_in[9];
    const float* b_f1  = (const float*)d_in[10];
    const float* w_f2  = (const float*)d_in[11];
    const float* b_f2  = (const float*)d_in[12];
    float* y = (float*)d_out;

    char* ws = (char*)d_ws;
    const size_t OFF_NQ  = 0;             // <=128 KB
    const size_t OFF_NK  = 131072;
    const size_t OFF_WQ  = 262144;        // 589,824 B
    const size_t OFF_WMG = 917504;        // 196,608 B
    const size_t OFF_WF1 = 1114112;       // 98,304 B
    const size_t OFF_WF2 = 1212416;       // 98,304 B
    const size_t OFF_X2  = 1310720;       // 16.78 MB -> ends 18,087,936
    const size_t OFF_XNT = 18087936;      // 8,519,680 -> ends 26,607,616
    const size_t OFF_CHUNK = 26607616;
    const size_t H_BYTES = 33554432;

    // per-chunk regions: Q, K, VT, ATTN; OUTB aliases Q (dead after attnw)
    int CH = 1;
    {
        const int cands[5] = {16, 8, 4, 2, 1};
        for (int ci = 0; ci < 5; ++ci) {
            int c = cands[ci];
            size_t qsz = (size_t)c * 4194304;
            size_t asz = (size_t)c * 1048576;
            size_t body = 3 * qsz + asz;
            if (body < H_BYTES) body = H_BYTES;
            if (OFF_CHUNK + body <= ws_size) { CH = c; break; }
        }
    }
    const size_t QSZ = (size_t)CH * 4194304;
    const size_t OFF_Q  = OFF_CHUNK;
    const size_t OFF_K  = OFF_Q + QSZ;
    const size_t OFF_VT = OFF_K + QSZ;
    const size_t OFF_AT = OFF_VT + QSZ;

    float* nqp = (float*)(ws + OFF_NQ);
    float* nkp = (float*)(ws + OFF_NK);
    unsigned short* wqb  = (unsigned short*)(ws + OFF_WQ);
    unsigned short* wmgb = (unsigned short*)(ws + OFF_WMG);
    unsigned short* wf1b = (unsigned short*)(ws + OFF_WF1);
    unsigned short* wf2b = (unsigned short*)(ws + OFF_WF2);
    float* x2  = (float*)(ws + OFF_X2);
    unsigned short* xnt  = (unsigned short*)(ws + OFF_XNT);
    unsigned short* qb   = (unsigned short*)(ws + OFF_Q);
    unsigned short* kb   = (unsigned short*)(ws + OFF_K);
    unsigned short* vtb  = (unsigned short*)(ws + OFF_VT);
    unsigned short* attn = (unsigned short*)(ws + OFF_AT);
    unsigned short* outb = (unsigned short*)(ws + OFF_Q);      // Q dead after attnw
    unsigned short* hbuf = (unsigned short*)(ws + OFF_CHUNK);  // after loop

    gnx_kernel<<<512, 256, 0, stream>>>(x, gn1_g, gn1_b, xnt);
    prep_w_kernel<<<384, 256, 0, stream>>>(w_qkv, wqb, 98304);
    prep_w_kernel<<<128, 256, 0, stream>>>(w_mg,  wmgb, 32768);
    prep_w_kernel<<<64,  256, 0, stream>>>(w_f1,  wf1b, 16384);
    prep_w_kernel<<<64,  256, 0, stream>>>(w_f2,  wf2b, 16384);
    const int nch = 16 / CH;
    for (int cidx = 0; cidx < nch; ++cidx) {
        int b0 = cidx * CH;
        conv_qkv_mfma<<<dim3(CH * 32, 12), 256, 0, stream>>>(xnt, wqb, b_qkv, qb, kb, vtb, nqp, nkp, b0);
        attnw_mfma<<<dim3(CH * 8, 2, 2), 256, 0, stream>>>(qb, kb, nqp, nkp, attn);
        pv_mfma_t<<<dim3(CH * 8, 2, 8), 256, 0, stream>>>(attn, vtb, outb);
        merge_mfma<<<CH * 32, 256, 0, stream>>>(outb, x, wmgb, b_mg, x2, b0);
    }
    gnx_kernel<<<512, 256, 0, stream>>>(x2, gn2_g, gn2_b, xnt);
    ff1_mfma<<<dim3(2, 512), 256, 0, stream>>>(xnt, wf1b, b_f1, hbuf);
    ff2_mfma<<<512, 256, 0, stream>>>(hbuf, x2, wf2b, b_f2, y);
}